// Round 6
// baseline (273.886 us; speedup 1.0000x reference)
//
#include <hip/hip_runtime.h>

#define NH 128
#define NW 128
#define ND 128
#define HWD (NH * NW * ND)
#define NWD (NW * ND)
#define NB 2

typedef float f32x2 __attribute__((ext_vector_type(2)));

#define SB() __builtin_amdgcn_sched_barrier(0)
#define LD1(dst, voff, base) asm volatile("global_load_dword %0, %1, %2" : "=v"(dst) : "v"(voff), "s"(base))
#define LD2(dst, voff, base) asm volatile("global_load_dwordx2 %0, %1, %2" : "=v"(dst) : "v"(voff), "s"(base))
#define TOUCH(x) asm volatile("" : "+v"(x))

__device__ __forceinline__ void newton6(float U[3][3]) {
#pragma unroll
    for (int it = 0; it < 6; ++it) {
        float c00 = U[1][1]*U[2][2] - U[1][2]*U[2][1];
        float c01 = U[0][2]*U[2][1] - U[0][1]*U[2][2];
        float c02 = U[0][1]*U[1][2] - U[0][2]*U[1][1];
        float c10 = U[1][2]*U[2][0] - U[1][0]*U[2][2];
        float c11 = U[0][0]*U[2][2] - U[0][2]*U[2][0];
        float c12 = U[0][2]*U[1][0] - U[0][0]*U[1][2];
        float c20 = U[1][0]*U[2][1] - U[1][1]*U[2][0];
        float c21 = U[0][1]*U[2][0] - U[0][0]*U[2][1];
        float c22 = U[0][0]*U[1][1] - U[0][1]*U[1][0];
        float det = U[0][0]*c00 + U[0][1]*c10 + U[0][2]*c20;

        float l    = __log2f(fabsf(det));                               // v_log_f32
        float zeta = __builtin_amdgcn_exp2f(-0.33333333333333333f * l); // v_exp_f32
        float s    = copysignf(zeta * zeta, det);
        float hz = 0.5f * zeta;
        float hs = 0.5f * s;

        float n00 = hz*U[0][0] + c00*hs;
        float n01 = hz*U[0][1] + c10*hs;
        float n02 = hz*U[0][2] + c20*hs;
        float n10 = hz*U[1][0] + c01*hs;
        float n11 = hz*U[1][1] + c11*hs;
        float n12 = hz*U[1][2] + c21*hs;
        float n20 = hz*U[2][0] + c02*hs;
        float n21 = hz*U[2][1] + c12*hs;
        float n22 = hz*U[2][2] + c22*hs;
        U[0][0]=n00; U[0][1]=n01; U[0][2]=n02;
        U[1][0]=n10; U[1][1]=n11; U[1][2]=n12;
        U[2][0]=n20; U[2][1]=n21; U[2][2]=n22;
    }
}

__device__ __forceinline__ void corner_setup(float cx, float cy, float cz,
                                             unsigned vo[4], float wA[4], float wB[4])
{
    float flx = floorf(cx), fly = floorf(cy), flz = floorf(cz);
    float fx = cx - flx, fy = cy - fly, fz = cz - flz;
    int x0 = (int)flx, y0 = (int)fly, z0 = (int)flz;
    int xa = min(max(x0,     0), NH - 1), xb = min(max(x0 + 1, 0), NH - 1);
    int ya = min(max(y0,     0), NW - 1), yb = min(max(y0 + 1, 0), NW - 1);
    int pa = min(max(z0, 0), ND - 2);      // z-pair base; clamp folded into weights
    vo[0] = (unsigned)(((xa * NW + ya) * ND) + pa) * 4u;
    vo[1] = (unsigned)(((xa * NW + yb) * ND) + pa) * 4u;
    vo[2] = (unsigned)(((xb * NW + ya) * ND) + pa) * 4u;
    vo[3] = (unsigned)(((xb * NW + yb) * ND) + pa) * 4u;
    float wza = 1.0f - fz, wzb = fz;
    float wv0 = ((z0 <= ND - 2) ? wza : 0.0f) + ((z0 <= -1) ? wzb : 0.0f);
    float wv1 = ((z0 >= ND - 1) ? wza : 0.0f) + ((z0 >=  0) ? wzb : 0.0f);
    float wxa = 1.0f - fx, wya = 1.0f - fy;
    float w0 = wxa * wya, w1 = wxa * fy, w2 = fx * wya, w3 = fx * fy;
    wA[0] = w0 * wv0; wA[1] = w1 * wv0; wA[2] = w2 * wv0; wA[3] = w3 * wv0;
    wB[0] = w0 * wv1; wB[1] = w1 * wv1; wB[2] = w2 * wv1; wB[3] = w3 * wv1;
}

__global__ __launch_bounds__(256) void warp_dti_kernel(
    const float* __restrict__ dti,
    const float* __restrict__ ddf,
    float* __restrict__ out)
{
    // Two voxels per thread: A = (hA, w, d) with hA in [0,64), B = (hA+64, w, d).
    // Grid: NB * 64 hA * 64 wpairs = 8192 blocks of 256 threads.
    const int blk   = blockIdx.x;
    const int b     = blk >> 12;              // scalar
    const int blkin = blk & 4095;
    const int tid   = threadIdx.x;
    const int d     = tid & (ND - 1);
    const int w     = ((blkin & 63) << 1) | (tid >> 7);  // wave-uniform
    const int hA    = blkin >> 6;             // 0..63, scalar
    const int hB    = hA + 64;
    const int spA   = (hA << 14) | (w << 7) | d;
    const unsigned vA = (unsigned)spA * 4u;
    const unsigned vB = vA + (unsigned)(64 * NWD * 4);

    const float* dch[3];
    const float* tch[6];
#pragma unroll
    for (int c = 0; c < 3; ++c) dch[c] = ddf + (size_t)(b * 3 + c) * HWD;
#pragma unroll
    for (int c = 0; c < 6; ++c) tch[c] = dti + (size_t)(b * 6 + c) * HWD;

    // clamped neighbor voffsets (boundary scale handled by shA/shB/sw/sd)
    const unsigned owm = (w > 0)      ? (unsigned)(-(ND * 4)) : 0u;   // wave-uniform
    const unsigned owp = (w < NW - 1) ? (unsigned)(ND * 4)    : 0u;
    const unsigned odm = (d > 0)      ? (unsigned)-4 : 0u;            // per-lane
    const unsigned odp = (d < ND - 1) ? 4u            : 0u;
    const unsigned vrmA = vA + ((hA > 0) ? (unsigned)(-(NWD * 4)) : 0u);
    const unsigned vrpA = vA + (unsigned)(NWD * 4);                   // hA<=63: always valid
    const unsigned vrmB = vB - (unsigned)(NWD * 4);                   // hB>=64: always valid
    const unsigned vrpB = vB + ((hB < NH - 1) ? (unsigned)(NWD * 4) : 0u);

    const float shA = (hA > 0)              ? 0.5f : 1.0f;
    const float shB = (hB < NH - 1)         ? 0.5f : 1.0f;
    const float sw  = (w > 0 && w < NW - 1) ? 0.5f : 1.0f;
    const float sd  = (d > 0 && d < ND - 1) ? 0.5f : 1.0f;

    // ==== FIFO ops 1-3: A centers ====
    float a_c[3];
#pragma unroll
    for (int c = 0; c < 3; ++c) LD1(a_c[c], vA, dch[c]);
    // ==== FIFO ops 4-21: A neighbors (18) ====
    float a_rm[3], a_rp[3], a_wm[3], a_wp[3], a_dm[3], a_dp[3];
#pragma unroll
    for (int c = 0; c < 3; ++c) {
        LD1(a_rm[c], vrmA,     dch[c]); LD1(a_rp[c], vrpA,     dch[c]);
        LD1(a_wm[c], vA + owm, dch[c]); LD1(a_wp[c], vA + owp, dch[c]);
        LD1(a_dm[c], vA + odm, dch[c]); LD1(a_dp[c], vA + odp, dch[c]);
    }

    // W1: drain A centers (pend 21 -> 18). Exposed stall (once per 2 voxels).
    asm volatile("s_waitcnt vmcnt(18)" ::: "memory"); SB();
#pragma unroll
    for (int c = 0; c < 3; ++c) TOUCH(a_c[c]);
    unsigned voA[4]; float wA0[4], wB0[4];
    corner_setup((float)hA + a_c[0], (float)w + a_c[1], (float)d + a_c[2], voA, wA0, wB0);
    SB();

    // ==== FIFO ops 22-45: gathers A (24 x dwordx2) ====
    f32x2 gA[6][4];
#pragma unroll
    for (int ch = 0; ch < 6; ++ch)
#pragma unroll
        for (int c = 0; c < 4; ++c) LD2(gA[ch][c], voA[c], tch[ch]);

    // W2: drain A neighbors (pend 42 -> 24); corner setup above was their shadow.
    asm volatile("s_waitcnt vmcnt(24)" ::: "memory"); SB();
#pragma unroll
    for (int c = 0; c < 3; ++c) {
        TOUCH(a_rm[c]); TOUCH(a_rp[c]); TOUCH(a_wm[c]);
        TOUCH(a_wp[c]); TOUCH(a_dm[c]); TOUCH(a_dp[c]);
    }
    float UA[3][3];
#pragma unroll
    for (int c = 0; c < 3; ++c) {
        UA[c][0] = shA * (a_rp[c] - a_rm[c]);
        UA[c][1] = sw  * (a_wp[c] - a_wm[c]);
        UA[c][2] = sd  * (a_dp[c] - a_dm[c]);
    }
    UA[0][0] += 1.0f; UA[1][1] += 1.0f; UA[2][2] += 1.0f;
    SB();

    // ==== FIFO ops 46-66: B ddf, centers(3) then neighbors(18) ====
    float b_c[3];
#pragma unroll
    for (int c = 0; c < 3; ++c) LD1(b_c[c], vB, dch[c]);
    float b_rm[3], b_rp[3], b_wm[3], b_wp[3], b_dm[3], b_dp[3];
#pragma unroll
    for (int c = 0; c < 3; ++c) {
        LD1(b_rm[c], vrmB,     dch[c]); LD1(b_rp[c], vrpB,     dch[c]);
        LD1(b_wm[c], vB + owm, dch[c]); LD1(b_wp[c], vB + owp, dch[c]);
        LD1(b_dm[c], vB + odm, dch[c]); LD1(b_dp[c], vB + odp, dch[c]);
    }
    SB();

    // Newton A: shadow for gathers A AND all B ddf loads (pend 24+21=45)
    newton6(UA);

    // W3: drain gathers A (pend 45 -> 21)
    asm volatile("s_waitcnt vmcnt(21)" ::: "memory"); SB();
#pragma unroll
    for (int ch = 0; ch < 6; ++ch)
#pragma unroll
        for (int c = 0; c < 4; ++c) TOUCH(gA[ch][c]);
    float accA[6] = {0.f, 0.f, 0.f, 0.f, 0.f, 0.f};
#pragma unroll
    for (int c = 0; c < 4; ++c)
#pragma unroll
        for (int ch = 0; ch < 6; ++ch)
            accA[ch] = fmaf(wA0[c], gA[ch][c].x, fmaf(wB0[c], gA[ch][c].y, accA[ch]));
    SB();

    // W4: drain B centers (pend 21 -> 18); they've had Newton-A's full latency.
    asm volatile("s_waitcnt vmcnt(18)" ::: "memory"); SB();
#pragma unroll
    for (int c = 0; c < 3; ++c) TOUCH(b_c[c]);
    unsigned voB[4]; float wA1[4], wB1[4];
    corner_setup((float)hB + b_c[0], (float)w + b_c[1], (float)d + b_c[2], voB, wA1, wB1);
    SB();

    // ==== FIFO ops 67-90: gathers B ====
    f32x2 gB[6][4];
#pragma unroll
    for (int ch = 0; ch < 6; ++ch)
#pragma unroll
        for (int c = 0; c < 4; ++c) LD2(gB[ch][c], voB[c], tch[ch]);

    // W5: drain B neighbors (pend 42 -> 24)
    asm volatile("s_waitcnt vmcnt(24)" ::: "memory"); SB();
#pragma unroll
    for (int c = 0; c < 3; ++c) {
        TOUCH(b_rm[c]); TOUCH(b_rp[c]); TOUCH(b_wm[c]);
        TOUCH(b_wp[c]); TOUCH(b_dm[c]); TOUCH(b_dp[c]);
    }
    float UB[3][3];
#pragma unroll
    for (int c = 0; c < 3; ++c) {
        UB[c][0] = shB * (b_rp[c] - b_rm[c]);
        UB[c][1] = sw  * (b_wp[c] - b_wm[c]);
        UB[c][2] = sd  * (b_dp[c] - b_dm[c]);
    }
    UB[0][0] += 1.0f; UB[1][1] += 1.0f; UB[2][2] += 1.0f;
    SB();

    // sandwich A + stores A (compiler stores; they enter vmcnt, drained only by W6)
    {
        float Dm00 = accA[0], Dm01 = accA[1], Dm02 = accA[3];
        float Dm11 = accA[2], Dm12 = accA[4], Dm22 = accA[5];
        float M[3][3];
#pragma unroll
        for (int i = 0; i < 3; ++i) {
            M[i][0] = UA[0][i]*Dm00 + UA[1][i]*Dm01 + UA[2][i]*Dm02;
            M[i][1] = UA[0][i]*Dm01 + UA[1][i]*Dm11 + UA[2][i]*Dm12;
            M[i][2] = UA[0][i]*Dm02 + UA[1][i]*Dm12 + UA[2][i]*Dm22;
        }
        float* obase = out + (size_t)b * 6 * HWD + spA;
        obase[0]       = M[0][0]*UA[0][0] + M[0][1]*UA[1][0] + M[0][2]*UA[2][0];
        obase[HWD]     = M[1][0]*UA[0][0] + M[1][1]*UA[1][0] + M[1][2]*UA[2][0];
        obase[2 * HWD] = M[1][0]*UA[0][1] + M[1][1]*UA[1][1] + M[1][2]*UA[2][1];
        obase[3 * HWD] = M[2][0]*UA[0][0] + M[2][1]*UA[1][0] + M[2][2]*UA[2][0];
        obase[4 * HWD] = M[2][0]*UA[0][1] + M[2][1]*UA[1][1] + M[2][2]*UA[2][1];
        obase[5 * HWD] = M[2][0]*UA[0][2] + M[2][1]*UA[1][2] + M[2][2]*UA[2][2];
    }

    // Newton B: shadow for gathers B
    newton6(UB);

    // W6: full drain (gathers B + A stores) — only vmcnt(0) spans stores.
    asm volatile("s_waitcnt vmcnt(0)" ::: "memory"); SB();
#pragma unroll
    for (int ch = 0; ch < 6; ++ch)
#pragma unroll
        for (int c = 0; c < 4; ++c) TOUCH(gB[ch][c]);
    float accB[6] = {0.f, 0.f, 0.f, 0.f, 0.f, 0.f};
#pragma unroll
    for (int c = 0; c < 4; ++c)
#pragma unroll
        for (int ch = 0; ch < 6; ++ch)
            accB[ch] = fmaf(wA1[c], gB[ch][c].x, fmaf(wB1[c], gB[ch][c].y, accB[ch]));

    {
        float Dm00 = accB[0], Dm01 = accB[1], Dm02 = accB[3];
        float Dm11 = accB[2], Dm12 = accB[4], Dm22 = accB[5];
        float M[3][3];
#pragma unroll
        for (int i = 0; i < 3; ++i) {
            M[i][0] = UB[0][i]*Dm00 + UB[1][i]*Dm01 + UB[2][i]*Dm02;
            M[i][1] = UB[0][i]*Dm01 + UB[1][i]*Dm11 + UB[2][i]*Dm12;
            M[i][2] = UB[0][i]*Dm02 + UB[1][i]*Dm12 + UB[2][i]*Dm22;
        }
        float* obase = out + (size_t)b * 6 * HWD + spA + 64 * NWD;
        obase[0]       = M[0][0]*UB[0][0] + M[0][1]*UB[1][0] + M[0][2]*UB[2][0];
        obase[HWD]     = M[1][0]*UB[0][0] + M[1][1]*UB[1][0] + M[1][2]*UB[2][0];
        obase[2 * HWD] = M[1][0]*UB[0][1] + M[1][1]*UB[1][1] + M[1][2]*UB[2][1];
        obase[3 * HWD] = M[2][0]*UB[0][0] + M[2][1]*UB[1][0] + M[2][2]*UB[2][0];
        obase[4 * HWD] = M[2][0]*UB[0][1] + M[2][1]*UB[1][1] + M[2][2]*UB[2][1];
        obase[5 * HWD] = M[2][0]*UB[0][2] + M[2][1]*UB[1][2] + M[2][2]*UB[2][2];
    }
}

extern "C" void kernel_launch(void* const* d_in, const int* in_sizes, int n_in,
                              void* d_out, int out_size, void* d_ws, size_t ws_size,
                              hipStream_t stream) {
    const float* dti = (const float*)d_in[0];
    const float* ddf = (const float*)d_in[1];
    float* o = (float*)d_out;
    const int nblocks = NB * 64 * 64;   // 8192 blocks x 256 threads = 2 voxels/thread
    warp_dti_kernel<<<nblocks, 256, 0, stream>>>(dti, ddf, o);
}

// Round 7
// 270.364 us; speedup vs baseline: 1.0130x; 1.0130x over previous
//
#include <hip/hip_runtime.h>

#define NH 128
#define NW 128
#define ND 128
#define HWD (NH * NW * ND)
#define NWD (NW * ND)
#define NB 2

typedef float f32x2 __attribute__((ext_vector_type(2)));

__global__ __launch_bounds__(256) void warp_dti_kernel(
    const float* __restrict__ dti,
    const float* __restrict__ ddf,
    float* __restrict__ out)
{
    // XCD-chunked bijective swizzle: 16384 blocks = 8 XCDs x 2048.
    // Hardware round-robins blockIdx across XCDs; this remap gives each XCD a
    // contiguous (b, h, wpair) slab so gather reuse lands in its private L2.
    const int blk0  = blockIdx.x;
    const int blk   = ((blk0 & 7) << 11) | (blk0 >> 3);

    const int b     = blk >> 13;              // scalar (SGPR)
    const int blkin = blk & 8191;
    const int tid   = threadIdx.x;
    const int sp    = (blkin << 8) | tid;
    const int d     = tid & (ND - 1);
    const int w     = ((blkin & 63) << 1) | (tid >> 7);  // wave-uniform
    const int h     = blkin >> 6;             // scalar (SGPR)

    const int dbase = b * 3 * HWD;            // scalar

    // ---- ddf loads: center + 6 clamped-offset neighbors per channel ----
    const int oh_m = (h > 0)      ? -NWD : 0;
    const int oh_p = (h < NH - 1) ?  NWD : 0;
    const int ow_m = (w > 0)      ? -ND  : 0;
    const int ow_p = (w < NW - 1) ?  ND  : 0;
    const int od_m = (d > 0)      ? -1   : 0;
    const int od_p = (d < ND - 1) ?  1   : 0;

    float uc[3], hm[3], hp[3], wm[3], wp[3], dm[3], dp[3];
#pragma unroll
    for (int c = 0; c < 3; ++c) {
        const float* p = ddf + dbase + c * HWD;
        uc[c] = p[sp];
        hm[c] = p[sp + oh_m];  hp[c] = p[sp + oh_p];
        wm[c] = p[sp + ow_m];  wp[c] = p[sp + ow_p];
        dm[c] = p[sp + od_m];  dp[c] = p[sp + od_p];
    }

    // ---- gradient -> U = I + grad(ddf): all compiler ddf waits land here,
    //      ABOVE the asm gather issue ----
    const float sh = (oh_m == 0 || oh_p == 0) ? 1.0f : 0.5f;
    const float sw = (ow_m == 0 || ow_p == 0) ? 1.0f : 0.5f;
    const float sd = (od_m == 0 || od_p == 0) ? 1.0f : 0.5f;

    float U[3][3];
#pragma unroll
    for (int c = 0; c < 3; ++c) {
        U[c][0] = sh * (hp[c] - hm[c]);
        U[c][1] = sw * (wp[c] - wm[c]);
        U[c][2] = sd * (dp[c] - dm[c]);
    }
    U[0][0] += 1.0f; U[1][1] += 1.0f; U[2][2] += 1.0f;

    // ---- trilinear corner setup (depends only on uc) ----
    const float cx = (float)h + uc[0];
    const float cy = (float)w + uc[1];
    const float cz = (float)d + uc[2];
    const float flx = floorf(cx), fly = floorf(cy), flz = floorf(cz);
    const float fx = cx - flx, fy = cy - fly, fz = cz - flz;
    const int x0 = (int)flx, y0 = (int)fly, z0 = (int)flz;
    const int xa = min(max(x0,     0), NH - 1), xb = min(max(x0 + 1, 0), NH - 1);
    const int ya = min(max(y0,     0), NW - 1), yb = min(max(y0 + 1, 0), NW - 1);
    const int pa = min(max(z0, 0), ND - 2);   // z-pair base; clamp folded into weights

    unsigned voffs[4];
    voffs[0] = (unsigned)(((xa * NW + ya) * ND) + pa) * 4u;
    voffs[1] = (unsigned)(((xa * NW + yb) * ND) + pa) * 4u;
    voffs[2] = (unsigned)(((xb * NW + ya) * ND) + pa) * 4u;
    voffs[3] = (unsigned)(((xb * NW + yb) * ND) + pa) * 4u;

    const float* bases[6];
#pragma unroll
    for (int ch = 0; ch < 6; ++ch)
        bases[ch] = dti + (size_t)(b * 6 + ch) * HWD;   // scalar bases (SGPR pairs)

    // ---- pin the gather issue HERE: volatile asm cannot be sunk ----
    __builtin_amdgcn_sched_barrier(0);
    f32x2 g[6][4];
#pragma unroll
    for (int ch = 0; ch < 6; ++ch)
#pragma unroll
        for (int c = 0; c < 4; ++c)
            asm volatile("global_load_dwordx2 %0, %1, %2"
                         : "=v"(g[ch][c])
                         : "v"(voffs[c]), "s"(bases[ch]));

    // ---- Newton polar runs in the gather latency shadow (pure VALU) ----
#pragma unroll
    for (int it = 0; it < 6; ++it) {
        float c00 = U[1][1]*U[2][2] - U[1][2]*U[2][1];
        float c01 = U[0][2]*U[2][1] - U[0][1]*U[2][2];
        float c02 = U[0][1]*U[1][2] - U[0][2]*U[1][1];
        float c10 = U[1][2]*U[2][0] - U[1][0]*U[2][2];
        float c11 = U[0][0]*U[2][2] - U[0][2]*U[2][0];
        float c12 = U[0][2]*U[1][0] - U[0][0]*U[1][2];
        float c20 = U[1][0]*U[2][1] - U[1][1]*U[2][0];
        float c21 = U[0][1]*U[2][0] - U[0][0]*U[2][1];
        float c22 = U[0][0]*U[1][1] - U[0][1]*U[1][0];
        float det = U[0][0]*c00 + U[0][1]*c10 + U[0][2]*c20;

        float l    = __log2f(fabsf(det));                               // v_log_f32
        float zeta = __builtin_amdgcn_exp2f(-0.33333333333333333f * l); // v_exp_f32
        float s    = copysignf(zeta * zeta, det);
        float hz = 0.5f * zeta;
        float hs = 0.5f * s;

        float n00 = hz*U[0][0] + c00*hs;
        float n01 = hz*U[0][1] + c10*hs;
        float n02 = hz*U[0][2] + c20*hs;
        float n10 = hz*U[1][0] + c01*hs;
        float n11 = hz*U[1][1] + c11*hs;
        float n12 = hz*U[1][2] + c21*hs;
        float n20 = hz*U[2][0] + c02*hs;
        float n21 = hz*U[2][1] + c12*hs;
        float n22 = hz*U[2][2] + c22*hs;
        U[0][0]=n00; U[0][1]=n01; U[0][2]=n02;
        U[1][0]=n10; U[1][1]=n11; U[1][2]=n12;
        U[2][0]=n20; U[2][1]=n21; U[2][2]=n22;
    }

    // ---- corner weights (VALU, still in the shadow) ----
    const float wza = 1.0f - fz, wzb = fz;
    const float wv0 = ((z0 <= ND - 2) ? wza : 0.0f) + ((z0 <= -1) ? wzb : 0.0f);
    const float wv1 = ((z0 >= ND - 1) ? wza : 0.0f) + ((z0 >=  0) ? wzb : 0.0f);
    const float wxa = 1.0f - fx, wya = 1.0f - fy;
    float wxy[4];
    wxy[0] = wxa * wya;  wxy[1] = wxa * fy;
    wxy[2] = fx  * wya;  wxy[3] = fx  * fy;
    float wA[4], wB[4];
#pragma unroll
    for (int c = 0; c < 4; ++c) { wA[c] = wxy[c] * wv0; wB[c] = wxy[c] * wv1; }

    // ---- drain gathers, then accumulate ----
    asm volatile("s_waitcnt vmcnt(0)" ::: "memory");
    __builtin_amdgcn_sched_barrier(0);

    float acc[6] = {0.f, 0.f, 0.f, 0.f, 0.f, 0.f};
#pragma unroll
    for (int c = 0; c < 4; ++c)
#pragma unroll
        for (int ch = 0; ch < 6; ++ch)
            acc[ch] = fmaf(wA[c], g[ch][c].x, fmaf(wB[c], g[ch][c].y, acc[ch]));

    // ---- T = R^T D R, output lower-tri ----
    float Dm[3][3];
    Dm[0][0] = acc[0]; Dm[0][1] = acc[1]; Dm[0][2] = acc[3];
    Dm[1][0] = acc[1]; Dm[1][1] = acc[2]; Dm[1][2] = acc[4];
    Dm[2][0] = acc[3]; Dm[2][1] = acc[4]; Dm[2][2] = acc[5];

    float M[3][3];
#pragma unroll
    for (int i = 0; i < 3; ++i)
#pragma unroll
        for (int k = 0; k < 3; ++k)
            M[i][k] = U[0][i]*Dm[0][k] + U[1][i]*Dm[1][k] + U[2][i]*Dm[2][k];

    float T00 = M[0][0]*U[0][0] + M[0][1]*U[1][0] + M[0][2]*U[2][0];
    float T10 = M[1][0]*U[0][0] + M[1][1]*U[1][0] + M[1][2]*U[2][0];
    float T11 = M[1][0]*U[0][1] + M[1][1]*U[1][1] + M[1][2]*U[2][1];
    float T20 = M[2][0]*U[0][0] + M[2][1]*U[1][0] + M[2][2]*U[2][0];
    float T21 = M[2][0]*U[0][1] + M[2][1]*U[1][1] + M[2][2]*U[2][1];
    float T22 = M[2][0]*U[0][2] + M[2][1]*U[1][2] + M[2][2]*U[2][2];

    const int obase = b * 6 * HWD;            // scalar
    out[obase + 0 * HWD + sp] = T00;
    out[obase + 1 * HWD + sp] = T10;
    out[obase + 2 * HWD + sp] = T11;
    out[obase + 3 * HWD + sp] = T20;
    out[obase + 4 * HWD + sp] = T21;
    out[obase + 5 * HWD + sp] = T22;
}

extern "C" void kernel_launch(void* const* d_in, const int* in_sizes, int n_in,
                              void* d_out, int out_size, void* d_ws, size_t ws_size,
                              hipStream_t stream) {
    const float* dti = (const float*)d_in[0];
    const float* ddf = (const float*)d_in[1];
    float* o = (float*)d_out;
    const int n = NB * HWD;   // 4,194,304 voxels
    warp_dti_kernel<<<n / 256, 256, 0, stream>>>(dti, ddf, o);
}

// Round 8
// 270.232 us; speedup vs baseline: 1.0135x; 1.0005x over previous
//
#include <hip/hip_runtime.h>

#define NH 128
#define NW 128
#define ND 128
#define HWD (NH * NW * ND)
#define NWD (NW * ND)
#define NB 2

typedef float f32x2 __attribute__((ext_vector_type(2)));

__global__ __launch_bounds__(256) void warp_dti_kernel(
    const float* __restrict__ dti,
    const float* __restrict__ ddf,
    float* __restrict__ out)
{
    // XCD-chunked bijective swizzle: 16384 blocks = 8 XCDs x 2048.
    const int blk0  = blockIdx.x;
    const int blk   = ((blk0 & 7) << 11) | (blk0 >> 3);

    const int b     = blk >> 13;              // scalar (SGPR)
    const int blkin = blk & 8191;
    const int tid   = threadIdx.x;
    const int sp    = (blkin << 8) | tid;
    const int d     = tid & (ND - 1);
    const int w     = ((blkin & 63) << 1) | (tid >> 7);  // wave-uniform
    const int h     = blkin >> 6;             // scalar (SGPR)

    const int dbase = b * 3 * HWD;            // scalar

    // ---- ddf loads: center + 6 clamped-offset neighbors per channel ----
    const int oh_m = (h > 0)      ? -NWD : 0;
    const int oh_p = (h < NH - 1) ?  NWD : 0;
    const int ow_m = (w > 0)      ? -ND  : 0;
    const int ow_p = (w < NW - 1) ?  ND  : 0;
    const int od_m = (d > 0)      ? -1   : 0;
    const int od_p = (d < ND - 1) ?  1   : 0;

    float uc[3], hm[3], hp[3], wm[3], wp[3], dm[3], dp[3];
#pragma unroll
    for (int c = 0; c < 3; ++c) {
        const float* p = ddf + dbase + c * HWD;
        uc[c] = p[sp];
        hm[c] = p[sp + oh_m];  hp[c] = p[sp + oh_p];
        wm[c] = p[sp + ow_m];  wp[c] = p[sp + ow_p];
        dm[c] = p[sp + od_m];  dp[c] = p[sp + od_p];
    }

    // ---- gradient -> U = I + grad(ddf) ----
    const float sh = (oh_m == 0 || oh_p == 0) ? 1.0f : 0.5f;
    const float sw = (ow_m == 0 || ow_p == 0) ? 1.0f : 0.5f;
    const float sd = (od_m == 0 || od_p == 0) ? 1.0f : 0.5f;

    float U[3][3];
#pragma unroll
    for (int c = 0; c < 3; ++c) {
        U[c][0] = sh * (hp[c] - hm[c]);
        U[c][1] = sw * (wp[c] - wm[c]);
        U[c][2] = sd * (dp[c] - dm[c]);
    }
    U[0][0] += 1.0f; U[1][1] += 1.0f; U[2][2] += 1.0f;

    // ---- trilinear corner setup (depends only on uc) ----
    const float cx = (float)h + uc[0];
    const float cy = (float)w + uc[1];
    const float cz = (float)d + uc[2];
    const float flx = floorf(cx), fly = floorf(cy), flz = floorf(cz);
    const float fx = cx - flx, fy = cy - fly, fz = cz - flz;
    const int x0 = (int)flx, y0 = (int)fly, z0 = (int)flz;
    const int xa = min(max(x0,     0), NH - 1), xb = min(max(x0 + 1, 0), NH - 1);
    const int ya = min(max(y0,     0), NW - 1), yb = min(max(y0 + 1, 0), NW - 1);
    const int pa = min(max(z0, 0), ND - 2);   // z-pair base; clamp folded into weights

    unsigned voffs[4];
    voffs[0] = (unsigned)(((xa * NW + ya) * ND) + pa) * 4u;
    voffs[1] = (unsigned)(((xa * NW + yb) * ND) + pa) * 4u;
    voffs[2] = (unsigned)(((xb * NW + ya) * ND) + pa) * 4u;
    voffs[3] = (unsigned)(((xb * NW + yb) * ND) + pa) * 4u;

    const float* bases[6];
#pragma unroll
    for (int ch = 0; ch < 6; ++ch)
        bases[ch] = dti + (size_t)(b * 6 + ch) * HWD;   // scalar bases (SGPR pairs)

    // ---- pin the gather issue HERE: volatile asm cannot be sunk ----
    __builtin_amdgcn_sched_barrier(0);
    f32x2 g[6][4];
#pragma unroll
    for (int ch = 0; ch < 6; ++ch)
#pragma unroll
        for (int c = 0; c < 4; ++c)
            asm volatile("global_load_dwordx2 %0, %1, %2"
                         : "=v"(g[ch][c])
                         : "v"(voffs[c]), "s"(bases[ch]));

    // ---- Newton polar in the gather latency shadow.
    //      4 iterations: input is I + E with ||E|| ~ 0.25; quadratic convergence
    //      reaches fp32 eps by iter 3 (e3 ~ 2e-8); iter 4 is safety margin.
    //      Iters 5-6 of the reference are numerically inert in fp32. ----
#pragma unroll
    for (int it = 0; it < 4; ++it) {
        float c00 = U[1][1]*U[2][2] - U[1][2]*U[2][1];
        float c01 = U[0][2]*U[2][1] - U[0][1]*U[2][2];
        float c02 = U[0][1]*U[1][2] - U[0][2]*U[1][1];
        float c10 = U[1][2]*U[2][0] - U[1][0]*U[2][2];
        float c11 = U[0][0]*U[2][2] - U[0][2]*U[2][0];
        float c12 = U[0][2]*U[1][0] - U[0][0]*U[1][2];
        float c20 = U[1][0]*U[2][1] - U[1][1]*U[2][0];
        float c21 = U[0][1]*U[2][0] - U[0][0]*U[2][1];
        float c22 = U[0][0]*U[1][1] - U[0][1]*U[1][0];
        float det = U[0][0]*c00 + U[0][1]*c10 + U[0][2]*c20;

        float l    = __log2f(fabsf(det));                               // v_log_f32
        float zeta = __builtin_amdgcn_exp2f(-0.33333333333333333f * l); // v_exp_f32
        float s    = copysignf(zeta * zeta, det);
        float hz = 0.5f * zeta;
        float hs = 0.5f * s;

        float n00 = hz*U[0][0] + c00*hs;
        float n01 = hz*U[0][1] + c10*hs;
        float n02 = hz*U[0][2] + c20*hs;
        float n10 = hz*U[1][0] + c01*hs;
        float n11 = hz*U[1][1] + c11*hs;
        float n12 = hz*U[1][2] + c21*hs;
        float n20 = hz*U[2][0] + c02*hs;
        float n21 = hz*U[2][1] + c12*hs;
        float n22 = hz*U[2][2] + c22*hs;
        U[0][0]=n00; U[0][1]=n01; U[0][2]=n02;
        U[1][0]=n10; U[1][1]=n11; U[1][2]=n12;
        U[2][0]=n20; U[2][1]=n21; U[2][2]=n22;
    }

    // ---- corner weights (VALU, still in the shadow) ----
    const float wza = 1.0f - fz, wzb = fz;
    const float wv0 = ((z0 <= ND - 2) ? wza : 0.0f) + ((z0 <= -1) ? wzb : 0.0f);
    const float wv1 = ((z0 >= ND - 1) ? wza : 0.0f) + ((z0 >=  0) ? wzb : 0.0f);
    const float wxa = 1.0f - fx, wya = 1.0f - fy;
    float wxy[4];
    wxy[0] = wxa * wya;  wxy[1] = wxa * fy;
    wxy[2] = fx  * wya;  wxy[3] = fx  * fy;
    float wA[4], wB[4];
#pragma unroll
    for (int c = 0; c < 4; ++c) { wA[c] = wxy[c] * wv0; wB[c] = wxy[c] * wv1; }

    // ---- drain gathers, then accumulate ----
    asm volatile("s_waitcnt vmcnt(0)" ::: "memory");
    __builtin_amdgcn_sched_barrier(0);

    float acc[6] = {0.f, 0.f, 0.f, 0.f, 0.f, 0.f};
#pragma unroll
    for (int c = 0; c < 4; ++c)
#pragma unroll
        for (int ch = 0; ch < 6; ++ch)
            acc[ch] = fmaf(wA[c], g[ch][c].x, fmaf(wB[c], g[ch][c].y, acc[ch]));

    // ---- T = R^T D R, output lower-tri ----
    float Dm[3][3];
    Dm[0][0] = acc[0]; Dm[0][1] = acc[1]; Dm[0][2] = acc[3];
    Dm[1][0] = acc[1]; Dm[1][1] = acc[2]; Dm[1][2] = acc[4];
    Dm[2][0] = acc[3]; Dm[2][1] = acc[4]; Dm[2][2] = acc[5];

    float M[3][3];
#pragma unroll
    for (int i = 0; i < 3; ++i)
#pragma unroll
        for (int k = 0; k < 3; ++k)
            M[i][k] = U[0][i]*Dm[0][k] + U[1][i]*Dm[1][k] + U[2][i]*Dm[2][k];

    float T00 = M[0][0]*U[0][0] + M[0][1]*U[1][0] + M[0][2]*U[2][0];
    float T10 = M[1][0]*U[0][0] + M[1][1]*U[1][0] + M[1][2]*U[2][0];
    float T11 = M[1][0]*U[0][1] + M[1][1]*U[1][1] + M[1][2]*U[2][1];
    float T20 = M[2][0]*U[0][0] + M[2][1]*U[1][0] + M[2][2]*U[2][0];
    float T21 = M[2][0]*U[0][1] + M[2][1]*U[1][1] + M[2][2]*U[2][1];
    float T22 = M[2][0]*U[0][2] + M[2][1]*U[1][2] + M[2][2]*U[2][2];

    const int obase = b * 6 * HWD;            // scalar
    out[obase + 0 * HWD + sp] = T00;
    out[obase + 1 * HWD + sp] = T10;
    out[obase + 2 * HWD + sp] = T11;
    out[obase + 3 * HWD + sp] = T20;
    out[obase + 4 * HWD + sp] = T21;
    out[obase + 5 * HWD + sp] = T22;
}

extern "C" void kernel_launch(void* const* d_in, const int* in_sizes, int n_in,
                              void* d_out, int out_size, void* d_ws, size_t ws_size,
                              hipStream_t stream) {
    const float* dti = (const float*)d_in[0];
    const float* ddf = (const float*)d_in[1];
    float* o = (float*)d_out;
    const int n = NB * HWD;   // 4,194,304 voxels
    warp_dti_kernel<<<n / 256, 256, 0, stream>>>(dti, ddf, o);
}